// Round 19
// baseline (45.816 us; speedup 1.0000x reference)
//
#include <hip/hip_runtime.h>
#include <hip/hip_bf16.h>

#define SEQ    2048
#define NHEAD  16
#define RPH    512          // rows per head = B*D
#define BK     64
#define NTH    512          // 8 waves: g = wv>>2 (quad group), tb = wv&3

#define WSTRIDE 2184        // elems per wrev copy; 2184 % 64 == 8 (bank spread)
#define ABUF_E  1024        // elems per A buffer (16 rows x 64 cols bf16)
#define WCOP_E  (8 * ABUF_E)                   // wcop after the EIGHT A buffers
#define TOT_E   (WCOP_E + 8 * WSTRIDE + 128)   // 25792 elems = 51584 B
// wbase staging (guard 0..7, data 8..2055, zero pad 2056..2215) aliases abufs

typedef float  f32x4  __attribute__((ext_vector_type(4)));
typedef __bf16 bf16x8 __attribute__((ext_vector_type(8)));

struct PF { float4 v0, v1; };

__device__ __forceinline__ unsigned f2bf(float f) {
    union { __hip_bfloat16 h; unsigned short u; } cv;
    cv.h = __float2bfloat16(f);
    return (unsigned)cv.u;
}

__device__ __forceinline__ uint4 pack8u(float4 a, float4 b) {
    union { bf16x8 v; uint4 u; } r;
    r.v[0] = (__bf16)a.x; r.v[1] = (__bf16)a.y;
    r.v[2] = (__bf16)a.z; r.v[3] = (__bf16)a.w;
    r.v[4] = (__bf16)b.x; r.v[5] = (__bf16)b.y;
    r.v[6] = (__bf16)b.z; r.v[7] = (__bf16)b.w;
    return r.u;
}

#define MFMA16(a, b, c) __builtin_amdgcn_mfma_f32_16x16x32_bf16((a), (b), (c), 0, 0, 0)

// Load this stager-thread's 1 row x 8 cols fp32 of chunk CH (stagers =
// tid<128: srow = tid>>3 (0..15), (tid&7)*8 = col base -> 16x64 tile).
#define LOADPF(P, CH)                                                         \
  { const float* g_ = Xp + (size_t)(CH) * BK;                                 \
    P.v0 = *(const float4*)g_;                                                \
    P.v1 = *(const float4*)(g_ + 4); }

// Pack+write this stager's row-slice into buffer AB (XOR-swizzled).
#define WRITEA(AB, P)  { *(uint4*)((AB) + wb0) = pack8u(P.v0, P.v1); }

// k-step 0 of chunk: A frag at k 0..31, B word (7-c) in slot 7-c (r14 map).
#define KSTEP0(ABC)                                                           \
  { bf16x8 af = *(const bf16x8*)((ABC) + Arow0 + (kq16 ^ swz));               \
    acc[0] = MFMA16(af, bw[7], acc[0]);                                       \
    acc[1] = MFMA16(af, bw[6], acc[1]);                                       \
    acc[2] = MFMA16(af, bw[5], acc[2]);                                       \
    acc[3] = MFMA16(af, bw[4], acc[3]);                                       \
    acc[4] = MFMA16(af, bw[3], acc[4]);                                       \
    acc[5] = MFMA16(af, bw[2], acc[5]);                                       \
    acc[6] = MFMA16(af, bw[1], acc[6]);                                       \
    acc[7] = MFMA16(af, bw[0], acc[7]); }

// k-step 1: A frag at k 32..63, B word (9-c); words 8,9 refilled into
// slots 0,1 after KSTEP0. Old-word MFMAs first (latency cover, r14 map).
#define KSTEP1(ABC)                                                           \
  { bf16x8 af = *(const bf16x8*)((ABC) + Arow0 + ((64 + kq16) ^ swz));        \
    acc[7] = MFMA16(af, bw[2], acc[7]);                                       \
    acc[6] = MFMA16(af, bw[3], acc[6]);                                       \
    acc[5] = MFMA16(af, bw[4], acc[5]);                                       \
    acc[4] = MFMA16(af, bw[5], acc[4]);                                       \
    acc[3] = MFMA16(af, bw[6], acc[3]);                                       \
    acc[2] = MFMA16(af, bw[7], acc[2]);                                       \
    acc[1] = MFMA16(af, bw[0], acc[1]);                                       \
    acc[0] = MFMA16(af, bw[1], acc[0]); }

// One chunk's MFMA work (guarded by this wave's extent nchw); flat B
// window: 8 words at chunk top, 2 refills mid-chunk (r14-proven).
#define CHUNKM(CH, ABC)                                                       \
  if ((CH) < nchw) {                                                          \
    const unsigned short* bq_ = wcB + 64 * (CH) - 112;                        \
    bw[0] = *(const bf16x8*)(bq_);                                            \
    bw[1] = *(const bf16x8*)(bq_ + 16);                                       \
    bw[2] = *(const bf16x8*)(bq_ + 32);                                       \
    bw[3] = *(const bf16x8*)(bq_ + 48);                                       \
    bw[4] = *(const bf16x8*)(bq_ + 64);                                       \
    bw[5] = *(const bf16x8*)(bq_ + 80);                                       \
    bw[6] = *(const bf16x8*)(bq_ + 96);                                       \
    bw[7] = *(const bf16x8*)(bq_ + 112);                                      \
    __builtin_amdgcn_s_setprio(1);                                            \
    KSTEP0(ABC);                                                              \
    bw[0] = *(const bf16x8*)(bq_ + 128);   /* word 8 */                       \
    bw[1] = *(const bf16x8*)(bq_ + 144);   /* word 9 */                       \
    KSTEP1(ABC);                                                              \
    __builtin_amdgcn_s_setprio(0);                                            \
  }

// One SUPERCHUNK = chunks CH, CH+1 (r17's counted-wait pipeline): MFMA
// from C0,C1 (staged 2 supers ago); stager writes for CH+4,CH+5 issued
// LAST; barrier waits lgkmcnt(2) so those 2 writes stay in flight.
#define SUPER(CH, C0, C1, N0, N1)                                             \
  {                                                                           \
    CHUNKM(CH, C0);                                                           \
    CHUNKM((CH) + 1, C1);                                                     \
    if (stager) {                                                             \
      WRITEA(N0, pfA);                     /* stage CH+4 (tail: inert) */     \
      WRITEA(N1, pfB);                     /* stage CH+5 (tail: inert) */     \
      if ((CH) + 6 < nch) LOADPF(pfA, (CH) + 6);                              \
      if ((CH) + 7 < nch) LOADPF(pfB, (CH) + 7);                              \
    }                                                                         \
    asm volatile("s_waitcnt lgkmcnt(2)\n\ts_barrier" ::: "memory");           \
  }

__global__ __launch_bounds__(NTH, 4) void mixer_kernel(
    const float* __restrict__ x, const float* __restrict__ wgt,
    const float* __restrict__ bias, float* __restrict__ out)
{
    __shared__ unsigned short smem[TOT_E] __attribute__((aligned(16)));
    char* b0 = (char*)smem;                     // A buffers (chunks mod 8)
    char* b1 = (char*)smem + ABUF_E * 2;
    char* b2 = (char*)smem + ABUF_E * 4;
    char* b3 = (char*)smem + ABUF_E * 6;
    char* b4 = (char*)smem + ABUF_E * 8;
    char* b5 = (char*)smem + ABUF_E * 10;
    char* b6 = (char*)smem + ABUF_E * 12;
    char* b7 = (char*)smem + ABUF_E * 14;
    unsigned short* wc = smem + WCOP_E;         // 8 shifted reversed-w copies

    const int tid  = threadIdx.x;
    const int lane = tid & 63;
    const int wv   = tid >> 6;                  // 0..7
    const int tb   = wv & 3;                    // col quarter within quad
    const int g    = wv >> 2;                   // quad group
    const bool stager = (tid < 128);            // waves 0,1 stage A

    // ---- block decode: 512 uniform blocks (48 chunks each) ----
    const int bid  = blockIdx.x;               // 0..511
    const int m    = (bid & 7) + 8 * ((bid >> 3) & 1);
    const int rt   = bid >> 4;                 // row tile 0..31 (16 rows)

    const float* Xb = x   + (size_t)(m * RPH + rt * 16) * SEQ;
    float*       Ob = out + (size_t)(m * RPH + rt * 16) * SEQ;
    const float* wr = wgt  + m * SEQ;
    const float* br = bias + m * SEQ;

    // ---- staging map (stagers only): 128 threads x float8 = 16x64 ----
    const int srow = tid >> 3;                 // 0..15 for stagers
    const int wsw  = (srow & 7) << 4;
    const int wb0  = srow * 128 + (((tid & 7) * 16) ^ wsw);
    const float* Xp = Xb + (size_t)srow * SEQ + (tid & 7) * 8;

    // ---- issue chunk-0/1 prefetch immediately (hides under prologue) ----
    PF pfA, pfB;
    if (stager) { LOADPF(pfA, 0); LOADPF(pfB, 1); }

    // ---- phase 1: reversed bf16 weights into abuf-alias (256 th) ----
    if (tid < 256) {
        const int t8 = tid * 8;                // 0..2040
        const float* gw = wr + (2040 - t8);
        float4 lo = *(const float4*)gw;
        float4 hi = *(const float4*)(gw + 4);
        uint4 v;
        v.x = f2bf(hi.w) | (f2bf(hi.z) << 16);
        v.y = f2bf(hi.y) | (f2bf(hi.x) << 16);
        v.z = f2bf(lo.w) | (f2bf(lo.z) << 16);
        v.w = f2bf(lo.y) | (f2bf(lo.x) << 16);
        *(uint4*)(smem + 8 + t8) = v;
        if (tid < 21) {                        // guard (8) + pad (160)
            uint4 z = {0u, 0u, 0u, 0u};
            unsigned short* dst = (tid == 0) ? smem
                                 : smem + 8 + 2048 + (tid - 1) * 8;
            *(uint4*)dst = z;
        }
    }
    __syncthreads();

    // ---- phase 2: 8 shifted copies, vectorized: copy_c[i] = wbase[i-c] ----
    #pragma unroll
    for (int c = 0; c < 8; ++c) {
        for (int grp = tid; grp < WSTRIDE / 8; grp += NTH) {
            const int i = grp * 8;
            uint4 g0 = *(const uint4*)(smem + 8 + i - 8);
            uint4 g1 = *(const uint4*)(smem + 8 + i);
            unsigned d[9] = {g0.x, g0.y, g0.z, g0.w,
                             g1.x, g1.y, g1.z, g1.w, 0u};
            const int qd = (16 - 2 * c) >> 2;
            uint4 o;
            if (c & 1) {
                o.x = (d[qd]     >> 16) | (d[qd + 1] << 16);
                o.y = (d[qd + 1] >> 16) | (d[qd + 2] << 16);
                o.z = (d[qd + 2] >> 16) | (d[qd + 3] << 16);
                o.w = (d[qd + 3] >> 16) | (d[qd + 4] << 16);
            } else {
                o.x = d[qd];     o.y = d[qd + 1];
                o.z = d[qd + 2]; o.w = d[qd + 3];
            }
            *(uint4*)(wc + c * WSTRIDE + i) = o;
        }
    }
    __syncthreads();   // wcop ready; wbase alias (abufs) free to overwrite

    // ---- per-lane MFMA constants ----
    const int col_low = lane & 15;
    const int kq      = lane >> 4;
    const int kq16    = kq * 16;
    const int swz     = (col_low & 7) << 4;
    const int cpy     = (col_low + 1) & 7;     // alignment class -> copy id
    const int BcBase  = cpy * WSTRIDE + cpy + 2047 - col_low + 8 * kq;
    const int Arow0   = col_low * 128;

    // ---- two nested K sweeps: {q3,q2} over 32 chunks, {q1,q0} over 16 ----
    #pragma unroll
    for (int sw = 0; sw < 2; ++sw) {
        const int q    = sw ? (g ? 0 : 1) : (g ? 2 : 3);
        const int nch  = sw ? 16 : 32;         // staged sweep length
        const int nchw = 8 * q + 2 * tb + 2;   // this wave's MFMA extent
        const int t0w  = 512 * q + 128 * tb;   // wave's col base
        const unsigned short* wcB = wc + (BcBase - t0w);

        // seed superchunks 0,1 (chunks 0..3); pf -> chunks 4,5 (nch >= 8)
        if (stager) {
            if (sw) { LOADPF(pfA, 0); LOADPF(pfB, 1); }
            WRITEA(b0, pfA);
            WRITEA(b1, pfB);
            LOADPF(pfA, 2);
            LOADPF(pfB, 3);
            WRITEA(b2, pfA);
            WRITEA(b3, pfB);
            LOADPF(pfA, 4);
            LOADPF(pfB, 5);
        }
        asm volatile("s_waitcnt lgkmcnt(0)\n\ts_barrier" ::: "memory");

        bf16x8 bw[8];
        f32x4 acc[8] = {};
        for (int ch = 0; ch < nch; ch += 8) {  // nch % 8 == 0
            SUPER(ch,     b0, b1, b4, b5);
            SUPER(ch + 2, b2, b3, b6, b7);
            SUPER(ch + 4, b4, b5, b0, b1);
            SUPER(ch + 6, b6, b7, b2, b3);
        }

        // epilogue: C/D layout col=lane&15, row=(lane>>4)*4+reg
        #pragma unroll
        for (int c = 0; c < 8; ++c) {
            const int colg = t0w + 16 * c + col_low;
            const float bv = br[colg];
            #pragma unroll
            for (int r = 0; r < 4; ++r)
                Ob[(size_t)(4 * kq + r) * SEQ + colg] = acc[c][r] + bv;
        }
        // next sweep's seed barrier (lgkmcnt 0) drains in-flight writes
        // before its bodies read the reseeded buffers.
    }
}

extern "C" void kernel_launch(void* const* d_in, const int* in_sizes, int n_in,
                              void* d_out, int out_size, void* d_ws, size_t ws_size,
                              hipStream_t stream) {
    const float* x  = (const float*)d_in[0];
    const float* w  = (const float*)d_in[1];
    const float* bs = (const float*)d_in[2];
    float* out = (float*)d_out;
    dim3 grid(512);    // 16 heads x 32 row tiles; each block = full col strip
    dim3 block(NTH);
    hipLaunchKernelGGL(mixer_kernel, grid, block, 0, stream, x, w, bs, out);
}

// Round 20
// 45.726 us; speedup vs baseline: 1.0020x; 1.0020x over previous
//
#include <hip/hip_runtime.h>
#include <hip/hip_bf16.h>

#define SEQ    2048
#define NHEAD  16
#define RPH    512          // rows per head = B*D
#define BK     64
#define NTH    512          // 8 waves: g = wv>>2 (quad group), tb = wv&3

#define WSTRIDE 2184        // elems per wrev copy; 2184 % 64 == 8 (bank spread)
#define ABUF_E  1024        // elems per A buffer (16 rows x 64 cols bf16)
#define WCOP_E  (8 * ABUF_E)                   // wcop after the EIGHT A buffers
#define TOT_E   (WCOP_E + 8 * WSTRIDE + 128)   // 25792 elems = 51584 B
// wbase staging (guard 0..7, data 8..2055, zero pad 2056..2215) aliases abufs

typedef float  f32x4  __attribute__((ext_vector_type(4)));
typedef __bf16 bf16x8 __attribute__((ext_vector_type(8)));

struct PF { float4 v0, v1; };

__device__ __forceinline__ unsigned f2bf(float f) {
    union { __hip_bfloat16 h; unsigned short u; } cv;
    cv.h = __float2bfloat16(f);
    return (unsigned)cv.u;
}

__device__ __forceinline__ uint4 pack8u(float4 a, float4 b) {
    union { bf16x8 v; uint4 u; } r;
    r.v[0] = (__bf16)a.x; r.v[1] = (__bf16)a.y;
    r.v[2] = (__bf16)a.z; r.v[3] = (__bf16)a.w;
    r.v[4] = (__bf16)b.x; r.v[5] = (__bf16)b.y;
    r.v[6] = (__bf16)b.z; r.v[7] = (__bf16)b.w;
    return r.u;
}

#define MFMA16(a, b, c) __builtin_amdgcn_mfma_f32_16x16x32_bf16((a), (b), (c), 0, 0, 0)

// Load this stager-thread's 1 row x 8 cols fp32 of chunk CH (stagers =
// tid<128: srow = tid>>3 (0..15), (tid&7)*8 = col base -> 16x64 tile).
#define LOADPF(P, CH)                                                         \
  { const float* g_ = Xp + (size_t)(CH) * BK;                                 \
    P.v0 = *(const float4*)g_;                                                \
    P.v1 = *(const float4*)(g_ + 4); }

// Pack+write this stager's row-slice into buffer AB (XOR-swizzled).
#define WRITEA(AB, P)  { *(uint4*)((AB) + wb0) = pack8u(P.v0, P.v1); }

// k-step 0 of chunk: A frag at k 0..31, B word (7-c) in slot 7-c (r14 map).
#define KSTEP0(ABC)                                                           \
  { bf16x8 af = *(const bf16x8*)((ABC) + Arow0 + (kq16 ^ swz));               \
    acc[0] = MFMA16(af, bw[7], acc[0]);                                       \
    acc[1] = MFMA16(af, bw[6], acc[1]);                                       \
    acc[2] = MFMA16(af, bw[5], acc[2]);                                       \
    acc[3] = MFMA16(af, bw[4], acc[3]);                                       \
    acc[4] = MFMA16(af, bw[3], acc[4]);                                       \
    acc[5] = MFMA16(af, bw[2], acc[5]);                                       \
    acc[6] = MFMA16(af, bw[1], acc[6]);                                       \
    acc[7] = MFMA16(af, bw[0], acc[7]); }

// k-step 1: A frag at k 32..63, B word (9-c); words 8,9 refilled into
// slots 0,1 after KSTEP0. Old-word MFMAs first (latency cover, r14 map).
#define KSTEP1(ABC)                                                           \
  { bf16x8 af = *(const bf16x8*)((ABC) + Arow0 + ((64 + kq16) ^ swz));        \
    acc[7] = MFMA16(af, bw[2], acc[7]);                                       \
    acc[6] = MFMA16(af, bw[3], acc[6]);                                       \
    acc[5] = MFMA16(af, bw[4], acc[5]);                                       \
    acc[4] = MFMA16(af, bw[5], acc[4]);                                       \
    acc[3] = MFMA16(af, bw[6], acc[3]);                                       \
    acc[2] = MFMA16(af, bw[7], acc[2]);                                       \
    acc[1] = MFMA16(af, bw[0], acc[1]);                                       \
    acc[0] = MFMA16(af, bw[1], acc[0]); }

// One chunk's MFMA work (guarded by this wave's extent nchw); flat B
// window: 8 words at chunk top, 2 refills mid-chunk (r14-proven).
#define CHUNKM(CH, ABC)                                                       \
  if ((CH) < nchw) {                                                          \
    const unsigned short* bq_ = wcB + 64 * (CH) - 112;                        \
    bw[0] = *(const bf16x8*)(bq_);                                            \
    bw[1] = *(const bf16x8*)(bq_ + 16);                                       \
    bw[2] = *(const bf16x8*)(bq_ + 32);                                       \
    bw[3] = *(const bf16x8*)(bq_ + 48);                                       \
    bw[4] = *(const bf16x8*)(bq_ + 64);                                       \
    bw[5] = *(const bf16x8*)(bq_ + 80);                                       \
    bw[6] = *(const bf16x8*)(bq_ + 96);                                       \
    bw[7] = *(const bf16x8*)(bq_ + 112);                                      \
    __builtin_amdgcn_s_setprio(1);                                            \
    KSTEP0(ABC);                                                              \
    bw[0] = *(const bf16x8*)(bq_ + 128);   /* word 8 */                       \
    bw[1] = *(const bf16x8*)(bq_ + 144);   /* word 9 */                       \
    KSTEP1(ABC);                                                              \
    __builtin_amdgcn_s_setprio(0);                                            \
  }

// One SUPERCHUNK = chunks CH, CH+1 (r17's counted-wait pipeline): MFMA
// from C0,C1 (staged 2 supers ago); stager writes for CH+4,CH+5 issued
// LAST; barrier waits lgkmcnt(2) so those 2 writes stay in flight.
#define SUPER(CH, C0, C1, N0, N1)                                             \
  {                                                                           \
    CHUNKM(CH, C0);                                                           \
    CHUNKM((CH) + 1, C1);                                                     \
    if (stager) {                                                             \
      WRITEA(N0, pfA);                     /* stage CH+4 (tail: inert) */     \
      WRITEA(N1, pfB);                     /* stage CH+5 (tail: inert) */     \
      if ((CH) + 6 < nch) LOADPF(pfA, (CH) + 6);                              \
      if ((CH) + 7 < nch) LOADPF(pfB, (CH) + 7);                              \
    }                                                                         \
    asm volatile("s_waitcnt lgkmcnt(2)\n\ts_barrier" ::: "memory");           \
  }

__global__ __launch_bounds__(NTH, 4) void mixer_kernel(
    const float* __restrict__ x, const float* __restrict__ wgt,
    const float* __restrict__ bias, float* __restrict__ out)
{
    __shared__ unsigned short smem[TOT_E] __attribute__((aligned(16)));
    char* b0 = (char*)smem;                     // A buffers (chunks mod 8)
    char* b1 = (char*)smem + ABUF_E * 2;
    char* b2 = (char*)smem + ABUF_E * 4;
    char* b3 = (char*)smem + ABUF_E * 6;
    char* b4 = (char*)smem + ABUF_E * 8;
    char* b5 = (char*)smem + ABUF_E * 10;
    char* b6 = (char*)smem + ABUF_E * 12;
    char* b7 = (char*)smem + ABUF_E * 14;
    unsigned short* wc = smem + WCOP_E;         // 8 shifted reversed-w copies

    const int tid  = threadIdx.x;
    const int lane = tid & 63;
    const int wv   = tid >> 6;                  // 0..7
    const int tb   = wv & 3;                    // col quarter within quad
    const int g    = wv >> 2;                   // quad group
    const bool stager = (tid < 128);            // waves 0,1 stage A

    // ---- block decode: 512 uniform blocks (48 chunks each) ----
    const int bid  = blockIdx.x;               // 0..511
    const int m    = (bid & 7) + 8 * ((bid >> 3) & 1);
    const int rt   = bid >> 4;                 // row tile 0..31 (16 rows)

    const float* Xb = x   + (size_t)(m * RPH + rt * 16) * SEQ;
    float*       Ob = out + (size_t)(m * RPH + rt * 16) * SEQ;
    const float* wr = wgt  + m * SEQ;
    const float* br = bias + m * SEQ;

    // ---- staging map (stagers only): 128 threads x float8 = 16x64 ----
    const int srow = tid >> 3;                 // 0..15 for stagers
    const int wsw  = (srow & 7) << 4;
    const int wb0  = srow * 128 + (((tid & 7) * 16) ^ wsw);
    const float* Xp = Xb + (size_t)srow * SEQ + (tid & 7) * 8;

    // ---- issue chunk-0/1 prefetch immediately (hides under prologue) ----
    PF pfA, pfB;
    if (stager) { LOADPF(pfA, 0); LOADPF(pfB, 1); }

    // ---- phase 1: reversed bf16 weights into abuf-alias (256 th) ----
    if (tid < 256) {
        const int t8 = tid * 8;                // 0..2040
        const float* gw = wr + (2040 - t8);
        float4 lo = *(const float4*)gw;
        float4 hi = *(const float4*)(gw + 4);
        uint4 v;
        v.x = f2bf(hi.w) | (f2bf(hi.z) << 16);
        v.y = f2bf(hi.y) | (f2bf(hi.x) << 16);
        v.z = f2bf(lo.w) | (f2bf(lo.z) << 16);
        v.w = f2bf(lo.y) | (f2bf(lo.x) << 16);
        *(uint4*)(smem + 8 + t8) = v;
        if (tid < 21) {                        // guard (8) + pad (160)
            uint4 z = {0u, 0u, 0u, 0u};
            unsigned short* dst = (tid == 0) ? smem
                                 : smem + 8 + 2048 + (tid - 1) * 8;
            *(uint4*)dst = z;
        }
    }
    __syncthreads();

    // ---- phase 2: 8 shifted copies, vectorized: copy_c[i] = wbase[i-c] ----
    #pragma unroll
    for (int c = 0; c < 8; ++c) {
        for (int grp = tid; grp < WSTRIDE / 8; grp += NTH) {
            const int i = grp * 8;
            uint4 g0 = *(const uint4*)(smem + 8 + i - 8);
            uint4 g1 = *(const uint4*)(smem + 8 + i);
            unsigned d[9] = {g0.x, g0.y, g0.z, g0.w,
                             g1.x, g1.y, g1.z, g1.w, 0u};
            const int qd = (16 - 2 * c) >> 2;
            uint4 o;
            if (c & 1) {
                o.x = (d[qd]     >> 16) | (d[qd + 1] << 16);
                o.y = (d[qd + 1] >> 16) | (d[qd + 2] << 16);
                o.z = (d[qd + 2] >> 16) | (d[qd + 3] << 16);
                o.w = (d[qd + 3] >> 16) | (d[qd + 4] << 16);
            } else {
                o.x = d[qd];     o.y = d[qd + 1];
                o.z = d[qd + 2]; o.w = d[qd + 3];
            }
            *(uint4*)(wc + c * WSTRIDE + i) = o;
        }
    }
    __syncthreads();   // wcop ready; wbase alias (abufs) free to overwrite

    // ---- per-lane MFMA constants ----
    const int col_low = lane & 15;
    const int kq      = lane >> 4;
    const int kq16    = kq * 16;
    const int swz     = (col_low & 7) << 4;
    const int cpy     = (col_low + 1) & 7;     // alignment class -> copy id
    const int BcBase  = cpy * WSTRIDE + cpy + 2047 - col_low + 8 * kq;
    const int Arow0   = col_low * 128;

    // ---- two nested K sweeps: {q3,q2} over 32 chunks, {q1,q0} over 16 ----
    #pragma unroll
    for (int sw = 0; sw < 2; ++sw) {
        const int q    = sw ? (g ? 0 : 1) : (g ? 2 : 3);
        const int nch  = sw ? 16 : 32;         // staged sweep length
        const int nchw = 8 * q + 2 * tb + 2;   // this wave's MFMA extent
        const int t0w  = 512 * q + 128 * tb;   // wave's col base
        const unsigned short* wcB = wc + (BcBase - t0w);

        // seed superchunks 0,1 (chunks 0..3); pf -> chunks 4,5 (nch >= 8)
        if (stager) {
            if (sw) { LOADPF(pfA, 0); LOADPF(pfB, 1); }
            WRITEA(b0, pfA);
            WRITEA(b1, pfB);
            LOADPF(pfA, 2);
            LOADPF(pfB, 3);
            WRITEA(b2, pfA);
            WRITEA(b3, pfB);
            LOADPF(pfA, 4);
            LOADPF(pfB, 5);
        }
        asm volatile("s_waitcnt lgkmcnt(0)\n\ts_barrier" ::: "memory");

        bf16x8 bw[8];
        f32x4 acc[8] = {};
        for (int ch = 0; ch < nch; ch += 8) {  // nch % 8 == 0
            SUPER(ch,     b0, b1, b4, b5);
            SUPER(ch + 2, b2, b3, b6, b7);
            SUPER(ch + 4, b4, b5, b0, b1);
            SUPER(ch + 6, b6, b7, b2, b3);
        }

        // epilogue: C/D layout col=lane&15, row=(lane>>4)*4+reg
        #pragma unroll
        for (int c = 0; c < 8; ++c) {
            const int colg = t0w + 16 * c + col_low;
            const float bv = br[colg];
            #pragma unroll
            for (int r = 0; r < 4; ++r)
                Ob[(size_t)(4 * kq + r) * SEQ + colg] = acc[c][r] + bv;
        }
        // next sweep's seed barrier (lgkmcnt 0) drains in-flight writes
        // before its bodies read the reseeded buffers.
    }
}

extern "C" void kernel_launch(void* const* d_in, const int* in_sizes, int n_in,
                              void* d_out, int out_size, void* d_ws, size_t ws_size,
                              hipStream_t stream) {
    const float* x  = (const float*)d_in[0];
    const float* w  = (const float*)d_in[1];
    const float* bs = (const float*)d_in[2];
    float* out = (float*)d_out;
    dim3 grid(512);    // 16 heads x 32 row tiles; each block = full col strip
    dim3 block(NTH);
    hipLaunchKernelGGL(mixer_kernel, grid, block, 0, stream, x, w, bs, out);
}